// Round 2
// baseline (914.249 us; speedup 1.0000x reference)
//
#include <hip/hip_runtime.h>
#include <math.h>

#define NEG_INF (-1e9f)
#define EPS 1e-5f

// ---------------- detect sparse_mask storage: int32 (0/1) vs packed bytes ----------------
__global__ void detect_mask_kernel(const unsigned int* __restrict__ sm, int* __restrict__ flag) {
    __shared__ int bad;
    if (threadIdx.x == 0) bad = 0;
    __syncthreads();
    for (int i = threadIdx.x; i < 4096; i += 256) {
        if (sm[i] > 1u) bad = 1;   // impossible for int32 bool storage
    }
    __syncthreads();
    if (threadIdx.x == 0) *flag = bad;   // 1 -> byte storage, 0 -> int32 storage
}

// ---------------- transpose: dst[c*R + r] = src[r*C + c] ----------------
__global__ void transpose_kernel(const float* __restrict__ src, float* __restrict__ dst,
                                 int R, int C) {
    int idx = blockIdx.x * 256 + threadIdx.x;
    if (idx < R * C) {
        int r = idx / C, c = idx % C;
        dst[c * R + r] = src[idx];
    }
}

// ---------------- QKV projection ----------------
// grid: B*L/16 = 512 blocks, block: 384 threads (one per output column)
__global__ void qkv_kernel(const float* __restrict__ h, const float* __restrict__ wT,
                           const float* __restrict__ bqkv,
                           float* __restrict__ qws, float* __restrict__ kws,
                           float* __restrict__ vws) {
    __shared__ __align__(16) float hs[16 * 128];
    const int tid = threadIdx.x;
    const int row0 = blockIdx.x * 16;
    for (int i = tid; i < 2048; i += 384) hs[i] = h[row0 * 128 + i];
    __syncthreads();

    const int c = tid;
    float acc[16];
#pragma unroll
    for (int r = 0; r < 16; ++r) acc[r] = 0.f;

    for (int d0 = 0; d0 < 128; d0 += 4) {
        float w0 = wT[(d0 + 0) * 384 + c];
        float w1 = wT[(d0 + 1) * 384 + c];
        float w2 = wT[(d0 + 2) * 384 + c];
        float w3 = wT[(d0 + 3) * 384 + c];
#pragma unroll
        for (int r = 0; r < 16; ++r) {
            float4 h4 = *reinterpret_cast<const float4*>(&hs[r * 128 + d0]);
            acc[r] = fmaf(w0, h4.x, acc[r]);
            acc[r] = fmaf(w1, h4.y, acc[r]);
            acc[r] = fmaf(w2, h4.z, acc[r]);
            acc[r] = fmaf(w3, h4.w, acc[r]);
        }
    }
    const int part = c >> 7;        // 0=q 1=k 2=v
    const int cc = c & 127;
    const int head = cc >> 5;
    const int dd = cc & 31;
    const float bias = bqkv[c];
    float* dstb = (part == 0) ? qws : ((part == 1) ? kws : vws);
    const float scale = (part == 0) ? 0.17677669529663687f : 1.0f; // 1/sqrt(32) folded into q
#pragma unroll
    for (int r = 0; r < 16; ++r) {
        int grow = row0 + r;
        int b = grow >> 11, l = grow & 2047;
        dstb[((b * 4 + head) * 2048 + l) * 32 + dd] = (acc[r] + bias) * scale;
    }
}

// ---------------- attention ----------------
// grid: B*H*(L/32) = 1024 blocks, block: 256 threads (4 waves, 8 q-rows per wave)
__global__ void attn_kernel(const float* __restrict__ qws, const float* __restrict__ kws,
                            const float* __restrict__ vws, const float* __restrict__ bias,
                            const unsigned char* __restrict__ sm8,
                            const int* __restrict__ sm32,
                            const int* __restrict__ smflag,
                            const float* __restrict__ nmask, float* __restrict__ aout) {
    __shared__ __align__(16) float q_lds[32 * 32];
    __shared__ __align__(16) float v_lds[64 * 33];
    __shared__ __align__(16) float p_lds[4 * 8 * 64];

    const int tid = threadIdx.x;
    const int wq = tid >> 6;
    const int lane = tid & 63;
    const int bh = blockIdx.x >> 6;   // b*4 + h
    const int qt = blockIdx.x & 63;
    const int q0 = qt * 32;
    const int b = bh >> 2;
    const int hh = bh & 3;
    const int bytemode = *smflag;     // uniform

    // stage Q tile (32 rows x 32 dims, contiguous in q_ws)
    for (int i = tid; i < 1024; i += 256) q_lds[i] = qws[(bh * 2048 + q0) * 32 + i];

    const int qbase = wq * 8;              // local first q-row of this wave
    const int H = lane >> 5;               // lane half
    const int dd = lane & 31;              // output dim owned by lane

    float m[8], lsum[8];
#pragma unroll
    for (int i = 0; i < 8; ++i) { m[i] = -3.0e38f; lsum[i] = 0.f; }
    float acc[4];
#pragma unroll
    for (int j = 0; j < 4; ++j) acc[j] = 0.f;

    for (int k0 = 0; k0 < 2048; k0 += 64) {
        __syncthreads();   // protect v_lds / p_lds from previous iteration's readers
        // stage V tile [64][33]
        for (int i = tid; i < 2048; i += 256)
            v_lds[(i >> 5) * 33 + (i & 31)] = vws[(bh * 2048 + k0) * 32 + i];

        const int k = k0 + lane;
        // K row -> registers (coalesced: 64 lanes cover 8KB contiguous)
        float4 kr[8];
        const float4* kp = reinterpret_cast<const float4*>(&kws[(bh * 2048 + k) * 32]);
#pragma unroll
        for (int i = 0; i < 8; ++i) kr[i] = kp[i];

        float s[8];
#pragma unroll
        for (int q = 0; q < 8; ++q) s[q] = 0.f;
#pragma unroll
        for (int d0 = 0; d0 < 8; ++d0) {
            float4 k4 = kr[d0];
#pragma unroll
            for (int q = 0; q < 8; ++q) {
                float4 q4 = *reinterpret_cast<const float4*>(&q_lds[(qbase + q) * 32 + d0 * 4]);
                s[q] = fmaf(q4.x, k4.x, s[q]);
                s[q] = fmaf(q4.y, k4.y, s[q]);
                s[q] = fmaf(q4.z, k4.z, s[q]);
                s[q] = fmaf(q4.w, k4.w, s[q]);
            }
        }
        const float keym = nmask[b * 2048 + k];
        if (bytemode) {
#pragma unroll
            for (int q = 0; q < 8; ++q) {
                int qrow = q0 + qbase + q;
                float bv = bias[(size_t)(bh * 2048 + qrow) * 2048 + k];
                int sm = sm8[(size_t)(b * 2048 + qrow) * 2048 + k];
                bool keep = (sm != 0) && (keym > 0.f);
                s[q] = keep ? (s[q] + bv) : NEG_INF;
            }
        } else {
#pragma unroll
            for (int q = 0; q < 8; ++q) {
                int qrow = q0 + qbase + q;
                float bv = bias[(size_t)(bh * 2048 + qrow) * 2048 + k];
                int sm = sm32[(size_t)(b * 2048 + qrow) * 2048 + k];
                bool keep = (sm != 0) && (keym > 0.f);
                s[q] = keep ? (s[q] + bv) : NEG_INF;
            }
        }
        // online softmax per q-row (full-wave reductions)
        float f[8], p[8];
#pragma unroll
        for (int q = 0; q < 8; ++q) {
            float tm = s[q];
#pragma unroll
            for (int off = 32; off > 0; off >>= 1) tm = fmaxf(tm, __shfl_xor(tm, off));
            float nm2 = fmaxf(m[q], tm);
            f[q] = __expf(m[q] - nm2);
            m[q] = nm2;
            float pv = __expf(s[q] - nm2);
            p[q] = pv;
            float ts = pv;
#pragma unroll
            for (int off = 32; off > 0; off >>= 1) ts += __shfl_xor(ts, off);
            lsum[q] = lsum[q] * f[q] + ts;
        }
#pragma unroll
        for (int j = 0; j < 4; ++j) {
            float fj = H ? f[4 + j] : f[j];
            acc[j] *= fj;
        }
#pragma unroll
        for (int q = 0; q < 8; ++q) p_lds[(wq * 8 + q) * 64 + lane] = p[q];
        __syncthreads();   // v_lds + p_lds ready

        // PV: lane (H, dd) accumulates 4 q-rows over 64 k
        const float* pw = &p_lds[(wq * 8 + H * 4) * 64];
#pragma unroll
        for (int kg = 0; kg < 64; kg += 4) {
            float pjf[4][4];
#pragma unroll
            for (int j = 0; j < 4; ++j) {
                float4 t = *reinterpret_cast<const float4*>(&pw[j * 64 + kg]);
                pjf[j][0] = t.x; pjf[j][1] = t.y; pjf[j][2] = t.z; pjf[j][3] = t.w;
            }
#pragma unroll
            for (int kk = 0; kk < 4; ++kk) {
                float v = v_lds[(kg + kk) * 33 + dd];
#pragma unroll
                for (int j = 0; j < 4; ++j) acc[j] = fmaf(pjf[j][kk], v, acc[j]);
            }
        }
    }
    // epilogue: normalize, apply query mask, write
#pragma unroll
    for (int j = 0; j < 4; ++j) {
        float lv = H ? lsum[4 + j] : lsum[j];
        int qrow = q0 + qbase + H * 4 + j;
        float nmq = nmask[b * 2048 + qrow];
        float val = (nmq > 0.f) ? acc[j] / lv : 0.f;
        aout[(size_t)(b * 2048 + qrow) * 128 + hh * 32 + dd] = val;
    }
}

// ---------------- LN stats helper (16 rows x 128 cols in LDS) ----------------
__device__ __forceinline__ void ln_stats(const float* buf, float* mu_s, float* rs_s, int tid) {
    int row = tid >> 4, sl = tid & 15;
    float4 x0 = *reinterpret_cast<const float4*>(&buf[row * 128 + sl * 8]);
    float4 x1 = *reinterpret_cast<const float4*>(&buf[row * 128 + sl * 8 + 4]);
    float sum = x0.x + x0.y + x0.z + x0.w + x1.x + x1.y + x1.z + x1.w;
    float sq = x0.x * x0.x + x0.y * x0.y + x0.z * x0.z + x0.w * x0.w +
               x1.x * x1.x + x1.y * x1.y + x1.z * x1.z + x1.w * x1.w;
#pragma unroll
    for (int off = 8; off > 0; off >>= 1) {
        sum += __shfl_xor(sum, off);
        sq += __shfl_xor(sq, off);
    }
    if (sl == 0) {
        float mu = sum * (1.f / 128.f);
        float var = sq * (1.f / 128.f) - mu * mu;
        mu_s[row] = mu;
        rs_s[row] = rsqrtf(var + EPS);
    }
}

// ---------------- fused epilogue: out-proj + res + LN1 + FFN + res + LN2 + mask ----------------
// grid: B*L/16 = 512 blocks, block: 256 threads
__global__ void epilogue_kernel(const float* __restrict__ aout, const float* __restrict__ h,
                                const float* __restrict__ woutT, const float* __restrict__ bout,
                                const float* __restrict__ wff1T, const float* __restrict__ bff1,
                                const float* __restrict__ wff2T, const float* __restrict__ bff2,
                                const float* __restrict__ g1, const float* __restrict__ b1,
                                const float* __restrict__ g2, const float* __restrict__ b2,
                                const float* __restrict__ nmask, float* __restrict__ out) {
    __shared__ __align__(16) float A[16 * 128];
    __shared__ __align__(16) float Hb[16 * 128];
    __shared__ __align__(16) float F[16 * 256];
    __shared__ float mu_s[16], rs_s[16];

    const int tid = threadIdx.x;
    const int row0 = blockIdx.x * 16;
    for (int i = tid; i < 2048; i += 256) {
        A[i] = aout[row0 * 128 + i];
        Hb[i] = h[row0 * 128 + i];
    }
    __syncthreads();

    const int g = tid >> 7, c = tid & 127;

    // --- out-projection ---
    float acc[8];
#pragma unroll
    for (int r = 0; r < 8; ++r) acc[r] = 0.f;
    for (int d0 = 0; d0 < 128; d0 += 4) {
        float w0 = woutT[(d0 + 0) * 128 + c];
        float w1 = woutT[(d0 + 1) * 128 + c];
        float w2 = woutT[(d0 + 2) * 128 + c];
        float w3 = woutT[(d0 + 3) * 128 + c];
#pragma unroll
        for (int r = 0; r < 8; ++r) {
            float4 a4 = *reinterpret_cast<const float4*>(&A[(g * 8 + r) * 128 + d0]);
            acc[r] = fmaf(w0, a4.x, acc[r]);
            acc[r] = fmaf(w1, a4.y, acc[r]);
            acc[r] = fmaf(w2, a4.z, acc[r]);
            acc[r] = fmaf(w3, a4.w, acc[r]);
        }
    }
    float bo = bout[c];
#pragma unroll
    for (int r = 0; r < 8; ++r) {
        int row = g * 8 + r;
        Hb[row * 128 + c] += acc[r] + bo;   // h + attn_out
    }
    __syncthreads();

    ln_stats(Hb, mu_s, rs_s, tid);
    __syncthreads();
    float g1c = g1[c], b1c = b1[c];
#pragma unroll
    for (int r = 0; r < 8; ++r) {
        int row = g * 8 + r;
        float v = (Hb[row * 128 + c] - mu_s[row]) * rs_s[row] * g1c + b1c;
        Hb[row * 128 + c] = v;              // h1
    }
    __syncthreads();

    // --- FF1 + ReLU (thread owns ff column j = tid) ---
    {
        const int j = tid;
        float a2[16];
#pragma unroll
        for (int r = 0; r < 16; ++r) a2[r] = 0.f;
        for (int d0 = 0; d0 < 128; d0 += 4) {
            float w0 = wff1T[(d0 + 0) * 256 + j];
            float w1 = wff1T[(d0 + 1) * 256 + j];
            float w2 = wff1T[(d0 + 2) * 256 + j];
            float w3 = wff1T[(d0 + 3) * 256 + j];
#pragma unroll
            for (int r = 0; r < 16; ++r) {
                float4 h4 = *reinterpret_cast<const float4*>(&Hb[r * 128 + d0]);
                a2[r] = fmaf(w0, h4.x, a2[r]);
                a2[r] = fmaf(w1, h4.y, a2[r]);
                a2[r] = fmaf(w2, h4.z, a2[r]);
                a2[r] = fmaf(w3, h4.w, a2[r]);
            }
        }
        float bj = bff1[j];
#pragma unroll
        for (int r = 0; r < 16; ++r) F[r * 256 + j] = fmaxf(a2[r] + bj, 0.f);
    }
    __syncthreads();

    // --- FF2 + residual ---
    float a3[8];
#pragma unroll
    for (int r = 0; r < 8; ++r) a3[r] = 0.f;
    for (int d0 = 0; d0 < 256; d0 += 4) {
        float w0 = wff2T[(d0 + 0) * 128 + c];
        float w1 = wff2T[(d0 + 1) * 128 + c];
        float w2 = wff2T[(d0 + 2) * 128 + c];
        float w3 = wff2T[(d0 + 3) * 128 + c];
#pragma unroll
        for (int r = 0; r < 8; ++r) {
            float4 f4 = *reinterpret_cast<const float4*>(&F[(g * 8 + r) * 256 + d0]);
            a3[r] = fmaf(w0, f4.x, a3[r]);
            a3[r] = fmaf(w1, f4.y, a3[r]);
            a3[r] = fmaf(w2, f4.z, a3[r]);
            a3[r] = fmaf(w3, f4.w, a3[r]);
        }
    }
    float bo2 = bff2[c];
#pragma unroll
    for (int r = 0; r < 8; ++r) {
        int row = g * 8 + r;
        A[row * 128 + c] = a3[r] + bo2 + Hb[row * 128 + c];   // h1 + ff
    }
    __syncthreads();

    ln_stats(A, mu_s, rs_s, tid);
    __syncthreads();
    float g2c = g2[c], b2c = b2[c];
#pragma unroll
    for (int r = 0; r < 8; ++r) {
        int row = g * 8 + r;
        float nm = nmask[row0 + row];
        float v = (A[row * 128 + c] - mu_s[row]) * rs_s[row] * g2c + b2c;
        out[(row0 + row) * 128 + c] = v * nm;
    }
}

extern "C" void kernel_launch(void* const* d_in, const int* in_sizes, int n_in,
                              void* d_out, int out_size, void* d_ws, size_t ws_size,
                              hipStream_t stream) {
    const float* h = (const float*)d_in[0];
    const float* bias = (const float*)d_in[1];
    const float* nmask = (const float*)d_in[2];
    const void* smask = d_in[3];                 // bool -> byte or int32 (detected)
    const float* w_qkv = (const float*)d_in[4];
    const float* b_qkv = (const float*)d_in[5];
    const float* w_out = (const float*)d_in[6];
    const float* b_out = (const float*)d_in[7];
    const float* w_ff1 = (const float*)d_in[8];
    const float* b_ff1 = (const float*)d_in[9];
    const float* w_ff2 = (const float*)d_in[10];
    const float* b_ff2 = (const float*)d_in[11];
    const float* g1 = (const float*)d_in[12];
    const float* b1 = (const float*)d_in[13];
    const float* g2 = (const float*)d_in[14];
    const float* b2 = (const float*)d_in[15];
    float* out = (float*)d_out;

    float* ws = (float*)d_ws;
    float* qws = ws;                       // 1M floats
    float* kws = ws + (1 << 20);           // 1M
    float* vws = ws + 2 * (1 << 20);       // 1M
    float* aoutw = ws + 3 * (1 << 20);     // 1M
    float* wqkvT = ws + 4 * (1 << 20);     // 384*128
    float* woutT = wqkvT + 384 * 128;      // 128*128
    float* wff1T = woutT + 128 * 128;      // 256*128
    float* wff2T = wff1T + 256 * 128;      // 128*256
    int* smflag = (int*)(wff2T + 128 * 256);

    detect_mask_kernel<<<1, 256, 0, stream>>>((const unsigned int*)smask, smflag);
    transpose_kernel<<<192, 256, 0, stream>>>(w_qkv, wqkvT, 384, 128);
    transpose_kernel<<<64, 256, 0, stream>>>(w_out, woutT, 128, 128);
    transpose_kernel<<<128, 256, 0, stream>>>(w_ff1, wff1T, 256, 128);
    transpose_kernel<<<128, 256, 0, stream>>>(w_ff2, wff2T, 128, 256);
    qkv_kernel<<<512, 384, 0, stream>>>(h, wqkvT, b_qkv, qws, kws, vws);
    attn_kernel<<<1024, 256, 0, stream>>>(qws, kws, vws, bias,
                                          (const unsigned char*)smask, (const int*)smask,
                                          smflag, nmask, aoutw);
    epilogue_kernel<<<512, 256, 0, stream>>>(aoutw, h, woutT, b_out, wff1T, b_ff1,
                                             wff2T, b_ff2, g1, b1, g2, b2, nmask, out);
}